// Round 7
// baseline (7679.698 us; speedup 1.0000x reference)
//
#include <hip/hip_runtime.h>

typedef _Float16 v8h __attribute__((ext_vector_type(8)));
typedef float v4f __attribute__((ext_vector_type(4)));
typedef unsigned int uint;

// ---- workspace layout (bytes) ----
#define OFF_BAR   0
#define OFF_AO0   4096
#define OFF_AO1   (OFF_AO0 + (1<<21))
#define OFF_AF0   (OFF_AO1 + (1<<21))
#define OFF_AF1   (OFF_AF0 + (1<<21))
#define OFF_W1    (OFF_AF1 + (1<<21))
#define OFF_W2    (OFF_W1 + (1<<21))
#define OFF_B1    (OFF_W2 + (1<<22))
#define OFF_B2    (OFF_B1 + 8192)

// Pack weights into MFMA B-fragment order:
// frag layout (16x16x32): n = nt*16 + (lane&15), k = k32*32 + (lane>>4)*8 + el
__global__ __launch_bounds__(256, 1)
void lstm_prep(const float* __restrict__ Whh1, const float* __restrict__ Wih2,
               const float* __restrict__ Whh2, const float* __restrict__ bih1,
               const float* __restrict__ bhh1, const float* __restrict__ bih2,
               const float* __restrict__ bhh2,
               _Float16* __restrict__ W1p, _Float16* __restrict__ W2p,
               float* __restrict__ bs1, float* __restrict__ bs2)
{
  const int total = 1048576 + 2097152 + 4096;
  for (int i = blockIdx.x*blockDim.x + threadIdx.x; i < total; i += gridDim.x*blockDim.x) {
    if (i < 1048576) {
      int nt = i >> 13, rem = i & 8191;
      int k32 = rem >> 9, c = rem & 511;
      int lane = c >> 3, el = c & 7;
      int n = nt*16 + (lane & 15);
      int k = k32*32 + (lane >> 4)*8 + el;
      W1p[i] = (_Float16)Whh1[n*512 + k];
    } else if (i < 3145728) {
      int j = i - 1048576;
      int nt = j >> 14, rem = j & 16383;
      int k32 = rem >> 9, c = rem & 511;
      int lane = c >> 3, el = c & 7;
      int n = nt*16 + (lane & 15);
      int k = k32*32 + (lane >> 4)*8 + el;
      float v = (k < 512) ? Wih2[n*512 + k] : Whh2[n*512 + (k - 512)];
      W2p[j] = (_Float16)v;
    } else {
      int n = i - 3145728;
      if (n < 2048) bs1[n] = bih1[n] + bhh1[n];
      else          bs2[n-2048] = bih2[n-2048] + bhh2[n-2048];
    }
  }
}

__device__ __forceinline__ float sigmoidf_(float z) { return 1.f / (1.f + __expf(-z)); }
__device__ __forceinline__ float tanhf_(float z)    { return 1.f - 2.f/(1.f + __expf(2.f*z)); }

// agent-scope relaxed 16B fragment load (2x8B): proven-correct exchange primitive
__device__ __forceinline__ v8h ld_frag_dev(const _Float16* base, uint off) {
  union { unsigned long long u[2]; v8h h; } cv;
  const unsigned long long* q = (const unsigned long long*)(base + off);
  cv.u[0] = __hip_atomic_load(q,     __ATOMIC_RELAXED, __HIP_MEMORY_SCOPE_AGENT);
  cv.u[1] = __hip_atomic_load(q + 1, __ATOMIC_RELAXED, __HIP_MEMORY_SCOPE_AGENT);
  return cv.h;
}

// 256 blocks x 512 threads, persistent, fused pipeline (162 rounds).
// Wave split: mtile(4) x cell(2), FULL K per wave -> MFMA C-layout places all
// 4 gates of an element in one lane (tt = gate*2+half, same reg) -> the entire
// LSTM epilogue runs IN REGISTERS (c-state lane-resident, bias + Wih1 frag
// preloaded). No K-reduce, no gred: only an 8.7KB/cell h-stash in LDS for the
// packed h-stores + out-projection. 2 syncs/round + barrier (was 7).
// A loads: double-buffered 8-chunk prefetch groups (MALL ~900cy path).
__global__ __launch_bounds__(512, 2)
void lstm_main(const float* __restrict__ x, const float* __restrict__ Wih1,
               const float* __restrict__ Wl, const float* __restrict__ blv,
               _Float16* __restrict__ AO0, _Float16* __restrict__ AO1,
               _Float16* __restrict__ AF0, _Float16* __restrict__ AF1,
               const _Float16* __restrict__ W1, const _Float16* __restrict__ W2,
               const float* __restrict__ bs1, const float* __restrict__ bs2,
               int* __restrict__ bar, float* __restrict__ out)
{
  __shared__ float stash[2*2176];   // [cell][row*34 + jj], stride 34 -> 2-way free
  const int tid  = threadIdx.x;
  const int wv   = tid >> 6, lane = tid & 63;
  const int quad = lane >> 4, lc = lane & 15;
  const int mtl  = wv & 3;          // wave's m-tile within block
  const int cw   = wv >> 2;         // 0 = cell1, 1 = cell2
  const int bid  = blockIdx.x;
  const int jg   = bid >> 3;
  const int ht   = (bid & 7)*2 + (jg >> 4);   // XCD swizzle
  const int bt   = jg & 15;

  _Float16* const AOv[2] = {AO0, AO1};
  _Float16* const AFv[2] = {AF0, AF1};

  const int mtile_g = bt*4 + mtl;
  // store ownership (tid>=256): tid2 -> (b_loc, oct)
  const int tid2  = tid - 256;
  const int b_loc = (tid2 >= 0) ? (tid2 >> 2) : 0, oct = tid2 & 3;
  const int m     = b_loc & 15, mtile_e = bt*4 + (b_loc >> 4);

  int ntg_[8];
  #pragma unroll
  for (int tt = 0; tt < 8; tt++) ntg_[tt] = (tt>>1)*32 + ht*2 + (tt&1);

  // preload bias (this wave's jj = {lc, 16+lc}) for both bias sets
  float bpre1[4][2], bpre2[4][2];
  #pragma unroll
  for (int g4 = 0; g4 < 4; g4++)
    #pragma unroll
    for (int h2 = 0; h2 < 2; h2++) {
      int hh = ht*32 + h2*16 + lc;
      bpre1[g4][h2] = bs1[g4*512 + hh];
      bpre2[g4][h2] = bs2[g4*512 + hh];
    }
  // preload Wih1 fragment (K=4) for this wave's jj (cell1 waves use it)
  v4f wxf[4][2];
  #pragma unroll
  for (int g4 = 0; g4 < 4; g4++)
    #pragma unroll
    for (int h2 = 0; h2 < 2; h2++) {
      int hh = ht*32 + h2*16 + lc;
      wxf[g4][h2] = *(const v4f*)(Wih1 + (size_t)(g4*512 + hh)*4);
    }

  // lane-resident cell state: [reg][half]
  float cst[4][2];
  #pragma unroll
  for (int rr = 0; rr < 4; rr++) { cst[rr][0] = 0.f; cst[rr][1] = 0.f; }

  const uint aoff0 = (uint)(mtile_g*32)*512 + lane*8;

  for (int r = 0; r < 162; r++) {
    const bool p1 = r < 129;
    const int  f  = r - 129;
    const int  wp = p1 ? (r & 1) : (f & 1);   // write parity
    const int  rp = wp ^ 1;                   // read parity
    const bool skipC = cw ? (r == 0 || r == 129) : (r == 128 || r == 161);

    // ---- this wave's GEMM (full K) ----
    const _Float16* Ac = cw ? AOv[rp] : (p1 ? AOv[rp] : AFv[rp]);
    const _Float16* Bc = cw ? W2 : (p1 ? W1 : W2);
    const int wk  = cw ? 32 : (p1 ? 16 : 32);
    const int nch = wk;                        // chunks = K/32
    const int ngr = nch >> 3;                  // groups of 8

    v4f acc[8];
    #pragma unroll
    for (int tt = 0; tt < 8; tt++) acc[tt] = (v4f){0,0,0,0};

    uint boff[8];
    #pragma unroll
    for (int tt = 0; tt < 8; tt++) boff[tt] = (uint)(ntg_[tt]*wk)*512 + lane*8;

    v8h abuf[2][8];
    #pragma unroll
    for (int j = 0; j < 8; j++) abuf[0][j] = ld_frag_dev(Ac, aoff0 + j*512);

    for (int g = 0; g < ngr; g++) {
      if (g + 1 < ngr) {
        #pragma unroll
        for (int j = 0; j < 8; j++)
          abuf[(g+1)&1][j] = ld_frag_dev(Ac, aoff0 + ((g+1)*8 + j)*512);
      }
      #pragma unroll
      for (int j = 0; j < 8; j++) {
        const v8h av = abuf[g&1][j];
        const uint ch = g*8 + j;
        #pragma unroll
        for (int tt = 0; tt < 8; tt++) {
          v8h bv = *(const v8h*)(Bc + boff[tt] + ch*512);
          acc[tt] = __builtin_amdgcn_mfma_f32_16x16x32_f16(av, bv, acc[tt], 0, 0, 0);
        }
      }
    }

    // ---- in-register LSTM epilogue ----
    // lane owns rows b = bt*64 + mtl*16 + quad*4 + reg, cols jj = {lc, 16+lc}
    const float* const bp1 = (cw == 0 && p1) ? &bpre1[0][0] : &bpre2[0][0];
    float xr[4][4];
    if (cw == 0 && p1 && r < 128) {
      #pragma unroll
      for (int rr = 0; rr < 4; rr++) {
        const int b = bt*64 + mtl*16 + quad*4 + rr;
        const v4f xv = *(const v4f*)(x + ((size_t)r*1024 + b)*4);
        #pragma unroll
        for (int j = 0; j < 4; j++) xr[rr][j] = xv[j];
      }
    }
    if (!skipC) {
      #pragma unroll
      for (int rr = 0; rr < 4; rr++) {
        #pragma unroll
        for (int h2 = 0; h2 < 2; h2++) {
          float g0 = acc[0 + h2][rr] + bp1[0*2 + h2];
          float g1 = acc[2 + h2][rr] + bp1[1*2 + h2];
          float g2 = acc[4 + h2][rr] + bp1[2*2 + h2];
          float g3 = acc[6 + h2][rr] + bp1[3*2 + h2];
          if (cw == 0 && p1 && r < 128) {
            g0 += xr[rr][0]*wxf[0][h2][0] + xr[rr][1]*wxf[0][h2][1] + xr[rr][2]*wxf[0][h2][2] + xr[rr][3]*wxf[0][h2][3];
            g1 += xr[rr][0]*wxf[1][h2][0] + xr[rr][1]*wxf[1][h2][1] + xr[rr][2]*wxf[1][h2][2] + xr[rr][3]*wxf[1][h2][3];
            g2 += xr[rr][0]*wxf[2][h2][0] + xr[rr][1]*wxf[2][h2][1] + xr[rr][2]*wxf[2][h2][2] + xr[rr][3]*wxf[2][h2][3];
            g3 += xr[rr][0]*wxf[3][h2][0] + xr[rr][1]*wxf[3][h2][1] + xr[rr][2]*wxf[3][h2][2] + xr[rr][3]*wxf[3][h2][3];
          }
          float ig = sigmoidf_(g0), fg = sigmoidf_(g1);
          float gg = tanhf_(g2),    og = sigmoidf_(g3);
          float c = fg*cst[rr][h2] + ig*gg;
          cst[rr][h2] = c;
          float hf = og * tanhf_(c);
          stash[cw*2176 + (mtl*16 + quad*4 + rr)*34 + h2*16 + lc] = hf;
        }
      }
    }
    __syncthreads();

    // ---- packed h stores (tid>=256) + out-projection (tid<256) ----
    const bool skip1 = (r == 128 || r == 161);
    const bool skip2 = (r == 0   || r == 129);
    if (tid >= 256) {
      auto st16 = [&](_Float16* bp, int chunk, unsigned long long u0, unsigned long long u1) {
        unsigned long long* p = (unsigned long long*)
          (bp + (((size_t)(mtile_e*32 + chunk)) << 9) + (oct*16 + m)*8);
        __hip_atomic_store(p,     u0, __ATOMIC_RELAXED, __HIP_MEMORY_SCOPE_AGENT);
        __hip_atomic_store(p + 1, u1, __ATOMIC_RELAXED, __HIP_MEMORY_SCOPE_AGENT);
      };
      if (!skip1) {                    // h1 from stash[0]
        v4f h0 = *(const v4f*)&stash[b_loc*34 + oct*8];
        v4f h1 = *(const v4f*)&stash[b_loc*34 + oct*8 + 4];
        union { _Float16 h8[8]; unsigned long long u[2]; } hu;
        #pragma unroll
        for (int j = 0; j < 4; j++) { hu.h8[j] = (_Float16)h0[j]; hu.h8[4+j] = (_Float16)h1[j]; }
        if (p1) {
          st16(AOv[wp], ht, hu.u[0], hu.u[1]);
          if (r == 127) st16(AFv[1], 16 + ht, hu.u[0], hu.u[1]);
        } else {
          st16(AFv[wp], 16 + ht, hu.u[0], hu.u[1]);
          st16(AOv[wp], ht, hu.u[0], hu.u[1]);
        }
      }
      if (!skip2) {                    // h2 from stash[1]
        v4f h0 = *(const v4f*)&stash[2176 + b_loc*34 + oct*8];
        v4f h1 = *(const v4f*)&stash[2176 + b_loc*34 + oct*8 + 4];
        union { _Float16 h8[8]; unsigned long long u[2]; } hu;
        #pragma unroll
        for (int j = 0; j < 4; j++) { hu.h8[j] = (_Float16)h0[j]; hu.h8[4+j] = (_Float16)h1[j]; }
        st16(AOv[wp], 16 + ht, hu.u[0], hu.u[1]);
        if (r == 128) { st16(AFv[0], ht, hu.u[0], hu.u[1]); st16(AFv[1], ht, hu.u[0], hu.u[1]); }
      }
    }
    if (tid < 256 && !p1 && r >= 130) {  // out(s) = h2f(s) @ Wl^T + bl, s = r-130
      const int s = r - 130;
      int bb = tid >> 2, o = tid & 3;
      float sa = (ht == 0) ? blv[o] : 0.f;
      const float* wl = Wl + (size_t)o*512 + ht*32;
      #pragma unroll
      for (int jj = 0; jj < 32; jj++) sa += stash[2176 + bb*34 + jj] * wl[jj];
      atomicAdd(&out[(((size_t)s*1024) + bt*64 + bb)*4 + o], sa);
    }
    __syncthreads();

    // ---- per-bt-group barrier: agent-relaxed add + relaxed poll ----
    if (tid == 0) {
      int* ctr = bar + bt*32;          // 128B-spaced counters
      __hip_atomic_fetch_add(ctr, 1, __ATOMIC_RELAXED, __HIP_MEMORY_SCOPE_AGENT);
      const int target = 16*(r+1);
      while (__hip_atomic_load(ctr, __ATOMIC_RELAXED, __HIP_MEMORY_SCOPE_AGENT) < target)
        __builtin_amdgcn_s_sleep(1);
    }
    __syncthreads();
  }
}

extern "C" void kernel_launch(void* const* d_in, const int* in_sizes, int n_in,
                              void* d_out, int out_size, void* d_ws, size_t ws_size,
                              hipStream_t stream) {
  const float* x    = (const float*)d_in[0];
  const float* Wih1 = (const float*)d_in[1];
  const float* Whh1 = (const float*)d_in[2];
  const float* bih1 = (const float*)d_in[3];
  const float* bhh1 = (const float*)d_in[4];
  const float* Wih2 = (const float*)d_in[5];
  const float* Whh2 = (const float*)d_in[6];
  const float* bih2 = (const float*)d_in[7];
  const float* bhh2 = (const float*)d_in[8];
  const float* Wl   = (const float*)d_in[9];
  const float* bl   = (const float*)d_in[10];

  char* ws = (char*)d_ws;
  int*      bar = (int*)(ws + OFF_BAR);
  _Float16* AO0 = (_Float16*)(ws + OFF_AO0);
  _Float16* AO1 = (_Float16*)(ws + OFF_AO1);
  _Float16* AF0 = (_Float16*)(ws + OFF_AF0);
  _Float16* AF1 = (_Float16*)(ws + OFF_AF1);
  _Float16* W1p = (_Float16*)(ws + OFF_W1);
  _Float16* W2p = (_Float16*)(ws + OFF_W2);
  float*    bs1 = (float*)(ws + OFF_B1);
  float*    bs2 = (float*)(ws + OFF_B2);

  // zero barrier + state buffers (h,c start at 0); zero out (atomic accumulation)
  hipMemsetAsync(ws, 0, (size_t)OFF_W1, stream);
  hipMemsetAsync(d_out, 0, (size_t)out_size * sizeof(float), stream);

  lstm_prep<<<2048, 256, 0, stream>>>(Whh1, Wih2, Whh2, bih1, bhh1, bih2, bhh2,
                                      W1p, W2p, bs1, bs2);
  lstm_main<<<256, 512, 0, stream>>>(x, Wih1, Wl, bl, AO0, AO1, AF0, AF1,
                                     W1p, W2p, bs1, bs2, bar, (float*)d_out);
}

// Round 8
// 7478.851 us; speedup vs baseline: 1.0269x; 1.0269x over previous
//
#include <hip/hip_runtime.h>

typedef _Float16 v8h __attribute__((ext_vector_type(8)));
typedef float v4f __attribute__((ext_vector_type(4)));
typedef unsigned int uint;

// ---- workspace layout (bytes) ----
#define OFF_BAR   0
#define OFF_AO0   4096
#define OFF_AO1   (OFF_AO0 + (1<<21))
#define OFF_AF0   (OFF_AO1 + (1<<21))
#define OFF_AF1   (OFF_AF0 + (1<<21))
#define OFF_W1    (OFF_AF1 + (1<<21))
#define OFF_W2    (OFF_W1 + (1<<21))
#define OFF_B1    (OFF_W2 + (1<<22))
#define OFF_B2    (OFF_B1 + 8192)

// Pack weights into MFMA B-fragment order:
// frag layout (16x16x32): n = nt*16 + (lane&15), k = k32*32 + (lane>>4)*8 + el
__global__ __launch_bounds__(256, 1)
void lstm_prep(const float* __restrict__ Whh1, const float* __restrict__ Wih2,
               const float* __restrict__ Whh2, const float* __restrict__ bih1,
               const float* __restrict__ bhh1, const float* __restrict__ bih2,
               const float* __restrict__ bhh2,
               _Float16* __restrict__ W1p, _Float16* __restrict__ W2p,
               float* __restrict__ bs1, float* __restrict__ bs2)
{
  const int total = 1048576 + 2097152 + 4096;
  for (int i = blockIdx.x*blockDim.x + threadIdx.x; i < total; i += gridDim.x*blockDim.x) {
    if (i < 1048576) {
      int nt = i >> 13, rem = i & 8191;
      int k32 = rem >> 9, c = rem & 511;
      int lane = c >> 3, el = c & 7;
      int n = nt*16 + (lane & 15);
      int k = k32*32 + (lane >> 4)*8 + el;
      W1p[i] = (_Float16)Whh1[n*512 + k];
    } else if (i < 3145728) {
      int j = i - 1048576;
      int nt = j >> 14, rem = j & 16383;
      int k32 = rem >> 9, c = rem & 511;
      int lane = c >> 3, el = c & 7;
      int n = nt*16 + (lane & 15);
      int k = k32*32 + (lane >> 4)*8 + el;
      float v = (k < 512) ? Wih2[n*512 + k] : Whh2[n*512 + (k - 512)];
      W2p[j] = (_Float16)v;
    } else {
      int n = i - 3145728;
      if (n < 2048) bs1[n] = bih1[n] + bhh1[n];
      else          bs2[n-2048] = bih2[n-2048] + bhh2[n-2048];
    }
  }
}

__device__ __forceinline__ float sigmoidf_(float z) { return 1.f / (1.f + __expf(-z)); }
__device__ __forceinline__ float tanhf_(float z)    { return 1.f - 2.f/(1.f + __expf(2.f*z)); }

// agent-scope relaxed 16B fragment load (2x8B): proven-correct exchange primitive
__device__ __forceinline__ v8h ld_frag_dev(const _Float16* base, uint off) {
  union { unsigned long long u[2]; v8h h; } cv;
  const unsigned long long* q = (const unsigned long long*)(base + off);
  cv.u[0] = __hip_atomic_load(q,     __ATOMIC_RELAXED, __HIP_MEMORY_SCOPE_AGENT);
  cv.u[1] = __hip_atomic_load(q + 1, __ATOMIC_RELAXED, __HIP_MEMORY_SCOPE_AGENT);
  return cv.h;
}

// Per-wave GEMM over NCH chunks, fully unrolled (compile-time trip count) so the
// 8-chunk double-buffered prefetch lives in REGISTERS. R7's runtime-indexed
// buffer (`abuf[g&1]` with runtime trip count) was demoted to scratch -> 15GB
// of HBM spill traffic. Template + #pragma unroll folds all indices statically.
template<int NCH>
__device__ __forceinline__ void gemm_wave(const _Float16* __restrict__ Ac,
                                          const _Float16* __restrict__ Bc,
                                          uint aoff0, const uint boff[8], v4f acc[8])
{
  constexpr int NG = NCH / 8;
  v8h buf[2][8];
  #pragma unroll
  for (int j = 0; j < 8; j++) buf[0][j] = ld_frag_dev(Ac, aoff0 + j*512);
  #pragma unroll
  for (int g = 0; g < NG; g++) {
    if (g + 1 < NG) {
      #pragma unroll
      for (int j = 0; j < 8; j++)
        buf[(g+1)&1][j] = ld_frag_dev(Ac, aoff0 + ((g+1)*8 + j)*512);
    }
    #pragma unroll
    for (int j = 0; j < 8; j++) {
      const v8h av = buf[g&1][j];
      const uint ch = g*8 + j;
      #pragma unroll
      for (int tt = 0; tt < 8; tt++) {
        v8h bv = *(const v8h*)(Bc + boff[tt] + ch*512);
        acc[tt] = __builtin_amdgcn_mfma_f32_16x16x32_f16(av, bv, acc[tt], 0, 0, 0);
      }
    }
  }
}

// 256 blocks x 512 threads, persistent, fused pipeline (162 rounds).
// Wave split: mtile(4) x cell(2), FULL K per wave -> all 4 gates of an element
// land in one lane -> LSTM epilogue entirely in registers (lane-resident c).
// Only an 8.7KB/cell h-stash in LDS for packed stores + out-projection.
__global__ __launch_bounds__(512, 2)
void lstm_main(const float* __restrict__ x, const float* __restrict__ Wih1,
               const float* __restrict__ Wl, const float* __restrict__ blv,
               _Float16* __restrict__ AO0, _Float16* __restrict__ AO1,
               _Float16* __restrict__ AF0, _Float16* __restrict__ AF1,
               const _Float16* __restrict__ W1, const _Float16* __restrict__ W2,
               const float* __restrict__ bs1, const float* __restrict__ bs2,
               int* __restrict__ bar, float* __restrict__ out)
{
  __shared__ float stash[2*2176];   // [cell][row*34 + jj], stride 34 -> 2-way free
  const int tid  = threadIdx.x;
  const int wv   = tid >> 6, lane = tid & 63;
  const int quad = lane >> 4, lc = lane & 15;
  const int mtl  = wv & 3;          // wave's m-tile within block
  const int cw   = wv >> 2;         // 0 = cell1, 1 = cell2
  const int bid  = blockIdx.x;
  const int jg   = bid >> 3;
  const int ht   = (bid & 7)*2 + (jg >> 4);   // XCD swizzle
  const int bt   = jg & 15;

  _Float16* const AOv[2] = {AO0, AO1};
  _Float16* const AFv[2] = {AF0, AF1};

  const int mtile_g = bt*4 + mtl;
  // store ownership (tid>=256): tid2 -> (b_loc, oct)
  const int tid2  = tid - 256;
  const int b_loc = (tid2 >= 0) ? (tid2 >> 2) : 0, oct = tid2 & 3;
  const int m     = b_loc & 15, mtile_e = bt*4 + (b_loc >> 4);

  int ntg_[8];
  #pragma unroll
  for (int tt = 0; tt < 8; tt++) ntg_[tt] = (tt>>1)*32 + ht*2 + (tt&1);

  // preload bias (this wave's jj = {lc, 16+lc}) for both bias sets
  float bpre1[4][2], bpre2[4][2];
  #pragma unroll
  for (int g4 = 0; g4 < 4; g4++)
    #pragma unroll
    for (int h2 = 0; h2 < 2; h2++) {
      int hh = ht*32 + h2*16 + lc;
      bpre1[g4][h2] = bs1[g4*512 + hh];
      bpre2[g4][h2] = bs2[g4*512 + hh];
    }
  // preload Wih1 fragment (K=4) for this wave's jj (cell1 waves use it)
  v4f wxf[4][2];
  #pragma unroll
  for (int g4 = 0; g4 < 4; g4++)
    #pragma unroll
    for (int h2 = 0; h2 < 2; h2++) {
      int hh = ht*32 + h2*16 + lc;
      wxf[g4][h2] = *(const v4f*)(Wih1 + (size_t)(g4*512 + hh)*4);
    }

  // lane-resident cell state: [reg][half]
  float cst[4][2];
  #pragma unroll
  for (int rr = 0; rr < 4; rr++) { cst[rr][0] = 0.f; cst[rr][1] = 0.f; }

  const uint aoff0 = (uint)(mtile_g*32)*512 + lane*8;

  for (int r = 0; r < 162; r++) {
    const bool p1 = r < 129;
    const int  f  = r - 129;
    const int  wp = p1 ? (r & 1) : (f & 1);   // write parity
    const int  rp = wp ^ 1;                   // read parity
    const bool skipC = cw ? (r == 0 || r == 129) : (r == 128 || r == 161);

    // ---- this wave's GEMM (full K) ----
    const _Float16* Ac = cw ? AOv[rp] : (p1 ? AOv[rp] : AFv[rp]);
    const _Float16* Bc = cw ? W2 : (p1 ? W1 : W2);
    const int wk  = cw ? 32 : (p1 ? 16 : 32);

    v4f acc[8];
    #pragma unroll
    for (int tt = 0; tt < 8; tt++) acc[tt] = (v4f){0,0,0,0};

    uint boff[8];
    #pragma unroll
    for (int tt = 0; tt < 8; tt++) boff[tt] = (uint)(ntg_[tt]*wk)*512 + lane*8;

    if (wk == 16) gemm_wave<16>(Ac, Bc, aoff0, boff, acc);
    else          gemm_wave<32>(Ac, Bc, aoff0, boff, acc);

    // ---- in-register LSTM epilogue ----
    // lane owns rows b = bt*64 + mtl*16 + quad*4 + reg, cols jj = {lc, 16+lc}
    const float* const bp1 = (cw == 0 && p1) ? &bpre1[0][0] : &bpre2[0][0];
    float xr[4][4];
    if (cw == 0 && p1 && r < 128) {
      #pragma unroll
      for (int rr = 0; rr < 4; rr++) {
        const int b = bt*64 + mtl*16 + quad*4 + rr;
        const v4f xv = *(const v4f*)(x + ((size_t)r*1024 + b)*4);
        #pragma unroll
        for (int j = 0; j < 4; j++) xr[rr][j] = xv[j];
      }
    }
    if (!skipC) {
      #pragma unroll
      for (int rr = 0; rr < 4; rr++) {
        #pragma unroll
        for (int h2 = 0; h2 < 2; h2++) {
          float g0 = acc[0 + h2][rr] + bp1[0*2 + h2];
          float g1 = acc[2 + h2][rr] + bp1[1*2 + h2];
          float g2 = acc[4 + h2][rr] + bp1[2*2 + h2];
          float g3 = acc[6 + h2][rr] + bp1[3*2 + h2];
          if (cw == 0 && p1 && r < 128) {
            g0 += xr[rr][0]*wxf[0][h2][0] + xr[rr][1]*wxf[0][h2][1] + xr[rr][2]*wxf[0][h2][2] + xr[rr][3]*wxf[0][h2][3];
            g1 += xr[rr][0]*wxf[1][h2][0] + xr[rr][1]*wxf[1][h2][1] + xr[rr][2]*wxf[1][h2][2] + xr[rr][3]*wxf[1][h2][3];
            g2 += xr[rr][0]*wxf[2][h2][0] + xr[rr][1]*wxf[2][h2][1] + xr[rr][2]*wxf[2][h2][2] + xr[rr][3]*wxf[2][h2][3];
            g3 += xr[rr][0]*wxf[3][h2][0] + xr[rr][1]*wxf[3][h2][1] + xr[rr][2]*wxf[3][h2][2] + xr[rr][3]*wxf[3][h2][3];
          }
          float ig = sigmoidf_(g0), fg = sigmoidf_(g1);
          float gg = tanhf_(g2),    og = sigmoidf_(g3);
          float c = fg*cst[rr][h2] + ig*gg;
          cst[rr][h2] = c;
          float hf = og * tanhf_(c);
          stash[cw*2176 + (mtl*16 + quad*4 + rr)*34 + h2*16 + lc] = hf;
        }
      }
    }
    __syncthreads();

    // ---- packed h stores (tid>=256) + out-projection (tid<256) ----
    const bool skip1 = (r == 128 || r == 161);
    const bool skip2 = (r == 0   || r == 129);
    if (tid >= 256) {
      auto st16 = [&](_Float16* bp, int chunk, unsigned long long u0, unsigned long long u1) {
        unsigned long long* p = (unsigned long long*)
          (bp + (((size_t)(mtile_e*32 + chunk)) << 9) + (oct*16 + m)*8);
        __hip_atomic_store(p,     u0, __ATOMIC_RELAXED, __HIP_MEMORY_SCOPE_AGENT);
        __hip_atomic_store(p + 1, u1, __ATOMIC_RELAXED, __HIP_MEMORY_SCOPE_AGENT);
      };
      if (!skip1) {                    // h1 from stash[0]
        v4f h0 = *(const v4f*)&stash[b_loc*34 + oct*8];
        v4f h1 = *(const v4f*)&stash[b_loc*34 + oct*8 + 4];
        union { _Float16 h8[8]; unsigned long long u[2]; } hu;
        #pragma unroll
        for (int j = 0; j < 4; j++) { hu.h8[j] = (_Float16)h0[j]; hu.h8[4+j] = (_Float16)h1[j]; }
        if (p1) {
          st16(AOv[wp], ht, hu.u[0], hu.u[1]);
          if (r == 127) st16(AFv[1], 16 + ht, hu.u[0], hu.u[1]);
        } else {
          st16(AFv[wp], 16 + ht, hu.u[0], hu.u[1]);
          st16(AOv[wp], ht, hu.u[0], hu.u[1]);
        }
      }
      if (!skip2) {                    // h2 from stash[1]
        v4f h0 = *(const v4f*)&stash[2176 + b_loc*34 + oct*8];
        v4f h1 = *(const v4f*)&stash[2176 + b_loc*34 + oct*8 + 4];
        union { _Float16 h8[8]; unsigned long long u[2]; } hu;
        #pragma unroll
        for (int j = 0; j < 4; j++) { hu.h8[j] = (_Float16)h0[j]; hu.h8[4+j] = (_Float16)h1[j]; }
        st16(AOv[wp], 16 + ht, hu.u[0], hu.u[1]);
        if (r == 128) { st16(AFv[0], ht, hu.u[0], hu.u[1]); st16(AFv[1], ht, hu.u[0], hu.u[1]); }
      }
    }
    if (tid < 256 && !p1 && r >= 130) {  // out(s) = h2f(s) @ Wl^T + bl, s = r-130
      const int s = r - 130;
      int bb = tid >> 2, o = tid & 3;
      float sa = (ht == 0) ? blv[o] : 0.f;
      const float* wl = Wl + (size_t)o*512 + ht*32;
      #pragma unroll
      for (int jj = 0; jj < 32; jj++) sa += stash[2176 + bb*34 + jj] * wl[jj];
      atomicAdd(&out[(((size_t)s*1024) + bt*64 + bb)*4 + o], sa);
    }
    __syncthreads();

    // ---- per-bt-group barrier: agent-relaxed add + relaxed poll ----
    if (tid == 0) {
      int* ctr = bar + bt*32;          // 128B-spaced counters
      __hip_atomic_fetch_add(ctr, 1, __ATOMIC_RELAXED, __HIP_MEMORY_SCOPE_AGENT);
      const int target = 16*(r+1);
      while (__hip_atomic_load(ctr, __ATOMIC_RELAXED, __HIP_MEMORY_SCOPE_AGENT) < target)
        __builtin_amdgcn_s_sleep(1);
    }
    __syncthreads();
  }
}

extern "C" void kernel_launch(void* const* d_in, const int* in_sizes, int n_in,
                              void* d_out, int out_size, void* d_ws, size_t ws_size,
                              hipStream_t stream) {
  const float* x    = (const float*)d_in[0];
  const float* Wih1 = (const float*)d_in[1];
  const float* Whh1 = (const float*)d_in[2];
  const float* bih1 = (const float*)d_in[3];
  const float* bhh1 = (const float*)d_in[4];
  const float* Wih2 = (const float*)d_in[5];
  const float* Whh2 = (const float*)d_in[6];
  const float* bih2 = (const float*)d_in[7];
  const float* bhh2 = (const float*)d_in[8];
  const float* Wl   = (const float*)d_in[9];
  const float* bl   = (const float*)d_in[10];

  char* ws = (char*)d_ws;
  int*      bar = (int*)(ws + OFF_BAR);
  _Float16* AO0 = (_Float16*)(ws + OFF_AO0);
  _Float16* AO1 = (_Float16*)(ws + OFF_AO1);
  _Float16* AF0 = (_Float16*)(ws + OFF_AF0);
  _Float16* AF1 = (_Float16*)(ws + OFF_AF1);
  _Float16* W1p = (_Float16*)(ws + OFF_W1);
  _Float16* W2p = (_Float16*)(ws + OFF_W2);
  float*    bs1 = (float*)(ws + OFF_B1);
  float*    bs2 = (float*)(ws + OFF_B2);

  // zero barrier + state buffers (h,c start at 0); zero out (atomic accumulation)
  hipMemsetAsync(ws, 0, (size_t)OFF_W1, stream);
  hipMemsetAsync(d_out, 0, (size_t)out_size * sizeof(float), stream);

  lstm_prep<<<2048, 256, 0, stream>>>(Whh1, Wih2, Whh2, bih1, bhh1, bih2, bhh2,
                                      W1p, W2p, bs1, bs2);
  lstm_main<<<256, 512, 0, stream>>>(x, Wih1, Wl, bl, AO0, AO1, AF0, AF1,
                                     W1p, W2p, bs1, bs2, bar, (float*)d_out);
}

// Round 9
// 4865.100 us; speedup vs baseline: 1.5785x; 1.5372x over previous
//
#include <hip/hip_runtime.h>

typedef _Float16 v8h __attribute__((ext_vector_type(8)));
typedef float v4f __attribute__((ext_vector_type(4)));
typedef unsigned int uint;

// ---- workspace layout (bytes) ----
#define OFF_BAR   0
#define OFF_AO0   4096
#define OFF_AO1   (OFF_AO0 + (1<<21))
#define OFF_AF0   (OFF_AO1 + (1<<21))
#define OFF_AF1   (OFF_AF0 + (1<<21))
#define OFF_W1    (OFF_AF1 + (1<<21))
#define OFF_W2    (OFF_W1 + (1<<21))
#define OFF_B1    (OFF_W2 + (1<<22))
#define OFF_B2    (OFF_B1 + 8192)

// Pack weights into MFMA B-fragment order:
// frag layout (16x16x32): n = nt*16 + (lane&15), k = k32*32 + (lane>>4)*8 + el
__global__ __launch_bounds__(256, 1)
void lstm_prep(const float* __restrict__ Whh1, const float* __restrict__ Wih2,
               const float* __restrict__ Whh2, const float* __restrict__ bih1,
               const float* __restrict__ bhh1, const float* __restrict__ bih2,
               const float* __restrict__ bhh2,
               _Float16* __restrict__ W1p, _Float16* __restrict__ W2p,
               float* __restrict__ bs1, float* __restrict__ bs2)
{
  const int total = 1048576 + 2097152 + 4096;
  for (int i = blockIdx.x*blockDim.x + threadIdx.x; i < total; i += gridDim.x*blockDim.x) {
    if (i < 1048576) {
      int nt = i >> 13, rem = i & 8191;
      int k32 = rem >> 9, c = rem & 511;
      int lane = c >> 3, el = c & 7;
      int n = nt*16 + (lane & 15);
      int k = k32*32 + (lane >> 4)*8 + el;
      W1p[i] = (_Float16)Whh1[n*512 + k];
    } else if (i < 3145728) {
      int j = i - 1048576;
      int nt = j >> 14, rem = j & 16383;
      int k32 = rem >> 9, c = rem & 511;
      int lane = c >> 3, el = c & 7;
      int n = nt*16 + (lane & 15);
      int k = k32*32 + (lane >> 4)*8 + el;
      float v = (k < 512) ? Wih2[n*512 + k] : Whh2[n*512 + (k - 512)];
      W2p[j] = (_Float16)v;
    } else {
      int n = i - 3145728;
      if (n < 2048) bs1[n] = bih1[n] + bhh1[n];
      else          bs2[n-2048] = bih2[n-2048] + bhh2[n-2048];
    }
  }
}

__device__ __forceinline__ float sigmoidf_(float z) { return 1.f / (1.f + __expf(-z)); }
__device__ __forceinline__ float tanhf_(float z)    { return 1.f - 2.f/(1.f + __expf(2.f*z)); }

// agent-scope relaxed 16B fragment load (2x8B): proven-correct exchange primitive
__device__ __forceinline__ v8h ld_frag_dev(const _Float16* base, uint off) {
  union { unsigned long long u[2]; v8h h; } cv;
  const unsigned long long* q = (const unsigned long long*)(base + off);
  cv.u[0] = __hip_atomic_load(q,     __ATOMIC_RELAXED, __HIP_MEMORY_SCOPE_AGENT);
  cv.u[1] = __hip_atomic_load(q + 1, __ATOMIC_RELAXED, __HIP_MEMORY_SCOPE_AGENT);
  return cv.h;
}

// Per-wave GEMM: 2 mtiles x 4 gate-tiles, NCH chunks, fully unrolled so the
// double-buffered A prefetch stays in registers (R7's runtime-trip loop spilled
// to scratch; R8 proved the template+unroll form is spill-free).
// rotg rotates the K-group iteration start per block/wave: the 16 blocks that
// stream the same weight slice (and the 2 dup-partner waves) read DIFFERENT
// addresses at any instant -> spreads L2 channel/bank load (de-hot-spot).
template<int NCH>
__device__ __forceinline__ void gemm2(const _Float16* __restrict__ Ac,
                                      const _Float16* __restrict__ Bc,
                                      uint a0, uint a1, const uint boff[4],
                                      int rotg, v4f acc[2][4])
{
  constexpr int NG = NCH / 4;       // groups of 4 chunks
  v8h A0[2][4], A1[2][4];
  {
    const uint base = (uint)rotg * 2048;   // rotg*4*512
    #pragma unroll
    for (int j = 0; j < 4; j++) {
      A0[0][j] = ld_frag_dev(Ac, a0 + base + j*512);
      A1[0][j] = ld_frag_dev(Ac, a1 + base + j*512);
    }
  }
  #pragma unroll
  for (int g = 0; g < NG; g++) {
    if (g + 1 < NG) {
      int gn = g + 1 + rotg; if (gn >= NG) gn -= NG;
      const uint nb = (uint)gn * 2048;
      #pragma unroll
      for (int j = 0; j < 4; j++) {
        A0[(g+1)&1][j] = ld_frag_dev(Ac, a0 + nb + j*512);
        A1[(g+1)&1][j] = ld_frag_dev(Ac, a1 + nb + j*512);
      }
    }
    int gg = g + rotg; if (gg >= NG) gg -= NG;
    const uint cb = (uint)gg * 2048;
    #pragma unroll
    for (int j = 0; j < 4; j++) {
      #pragma unroll
      for (int t = 0; t < 4; t++) {
        v8h bv = *(const v8h*)(Bc + boff[t] + cb + j*512);
        acc[0][t] = __builtin_amdgcn_mfma_f32_16x16x32_f16(A0[g&1][j], bv, acc[0][t], 0, 0, 0);
        acc[1][t] = __builtin_amdgcn_mfma_f32_16x16x32_f16(A1[g&1][j], bv, acc[1][t], 0, 0, 0);
      }
    }
  }
}

// 256 blocks x 512 threads, persistent, fused pipeline (162 rounds).
// Wave split: cell(2) x mtile-pair(2) x col-half(2). Each wave: 2 mtiles x
// 4 gate-tiles (its col-half) over FULL K -> B-dup=2 (halved vs R8), 2 MFMA
// per B-load, and the wave still holds ALL 4 gates of its columns -> the LSTM
// epilogue stays entirely in registers (lane-resident c-state).
// LDS: only the 2x8.7KB h-stash for packed stores + out-projection.
__global__ __launch_bounds__(512, 2)
void lstm_main(const float* __restrict__ x, const float* __restrict__ Wih1,
               const float* __restrict__ Wl, const float* __restrict__ blv,
               _Float16* __restrict__ AO0, _Float16* __restrict__ AO1,
               _Float16* __restrict__ AF0, _Float16* __restrict__ AF1,
               const _Float16* __restrict__ W1, const _Float16* __restrict__ W2,
               const float* __restrict__ bs1, const float* __restrict__ bs2,
               int* __restrict__ bar, float* __restrict__ out)
{
  __shared__ float stash[2*2176];   // [cell][row*34 + jj], stride 34 -> 2-way free
  const int tid  = threadIdx.x;
  const int wv   = tid >> 6, lane = tid & 63;
  const int quad = lane >> 4, lc = lane & 15;
  const int cw   = wv >> 2;         // 0 = cell1, 1 = cell2  (SIMD pairs cell1+cell2)
  const int mp   = (wv >> 1) & 1;   // mtile pair {mp*2, mp*2+1}
  const int hf   = wv & 1;          // column half (jj = hf*16 + lc)
  const int bid  = blockIdx.x;
  const int jg   = bid >> 3;
  const int ht   = (bid & 7)*2 + (jg >> 4);   // XCD swizzle
  const int bt   = jg & 15;

  _Float16* const AOv[2] = {AO0, AO1};
  _Float16* const AFv[2] = {AF0, AF1};

  // store ownership (tid>=256): tid2 -> (b_loc, oct)
  const int tid2  = tid - 256;
  const int b_loc = (tid2 >= 0) ? (tid2 >> 2) : 0, oct = tid2 & 3;
  const int m     = b_loc & 15, mtile_e = bt*4 + (b_loc >> 4);

  // rotation starts (dup-partner waves offset by half the ring)
  const int rot16 = (bt + mp*2) & 3;   // NG=4  (K=512)
  const int rot32 = (bt + mp*4) & 7;   // NG=8  (K=1024)

  // this wave's 4 gate-tiles: ntg(g4) = g4*32 + ht*2 + hf
  int ntg_[4];
  #pragma unroll
  for (int g4 = 0; g4 < 4; g4++) ntg_[g4] = g4*32 + ht*2 + hf;

  // this lane's column: jj = hf*16 + lc, hh = ht*32 + jj
  const int hh = ht*32 + hf*16 + lc;

  // preload biases + Wih1 column fragment (K=4)
  float bpre1[4], bpre2[4];
  v4f wxf[4];
  #pragma unroll
  for (int g4 = 0; g4 < 4; g4++) {
    bpre1[g4] = bs1[g4*512 + hh];
    bpre2[g4] = bs2[g4*512 + hh];
    wxf[g4]   = *(const v4f*)(Wih1 + (size_t)(g4*512 + hh)*4);
  }

  // lane-resident cell state: [mtile i2][reg rr]
  float cst[2][4];
  #pragma unroll
  for (int i2 = 0; i2 < 2; i2++)
    #pragma unroll
    for (int rr = 0; rr < 4; rr++) cst[i2][rr] = 0.f;

  const uint a0 = (uint)((bt*4 + mp*2    )*32)*512 + lane*8;
  const uint a1 = (uint)((bt*4 + mp*2 + 1)*32)*512 + lane*8;

  for (int r = 0; r < 162; r++) {
    const bool p1 = r < 129;
    const int  f  = r - 129;
    const int  wp = p1 ? (r & 1) : (f & 1);   // write parity
    const int  rp = wp ^ 1;                   // read parity
    const bool skipC = cw ? (r == 0 || r == 129) : (r == 128 || r == 161);

    // ---- this wave's GEMM (full K, 2 mtiles x 4 gate-tiles) ----
    const _Float16* Ac = cw ? AOv[rp] : (p1 ? AOv[rp] : AFv[rp]);
    const _Float16* Bc = cw ? W2 : (p1 ? W1 : W2);
    const int wk  = cw ? 32 : (p1 ? 16 : 32);

    v4f acc[2][4];
    #pragma unroll
    for (int i2 = 0; i2 < 2; i2++)
      #pragma unroll
      for (int t = 0; t < 4; t++) acc[i2][t] = (v4f){0,0,0,0};

    uint boff[4];
    #pragma unroll
    for (int t = 0; t < 4; t++) boff[t] = (uint)(ntg_[t]*wk)*512 + lane*8;

    if (wk == 16) gemm2<16>(Ac, Bc, a0, a1, boff, rot16, acc);
    else          gemm2<32>(Ac, Bc, a0, a1, boff, rot32, acc);

    // ---- in-register LSTM epilogue ----
    // lane owns rows b = bt*64 + (mp*2+i2)*16 + quad*4 + rr, single col hh
    const float* const bp = (cw == 0 && p1) ? bpre1 : bpre2;
    float xr[2][4][4];
    if (cw == 0 && p1 && r < 128) {
      #pragma unroll
      for (int i2 = 0; i2 < 2; i2++)
        #pragma unroll
        for (int rr = 0; rr < 4; rr++) {
          const int b = bt*64 + (mp*2 + i2)*16 + quad*4 + rr;
          const v4f xv = *(const v4f*)(x + ((size_t)r*1024 + b)*4);
          #pragma unroll
          for (int j = 0; j < 4; j++) xr[i2][rr][j] = xv[j];
        }
    }
    if (!skipC) {
      #pragma unroll
      for (int i2 = 0; i2 < 2; i2++) {
        #pragma unroll
        for (int rr = 0; rr < 4; rr++) {
          float g0 = acc[i2][0][rr] + bp[0];
          float g1 = acc[i2][1][rr] + bp[1];
          float g2 = acc[i2][2][rr] + bp[2];
          float g3 = acc[i2][3][rr] + bp[3];
          if (cw == 0 && p1 && r < 128) {
            g0 += xr[i2][rr][0]*wxf[0][0] + xr[i2][rr][1]*wxf[0][1] + xr[i2][rr][2]*wxf[0][2] + xr[i2][rr][3]*wxf[0][3];
            g1 += xr[i2][rr][0]*wxf[1][0] + xr[i2][rr][1]*wxf[1][1] + xr[i2][rr][2]*wxf[1][2] + xr[i2][rr][3]*wxf[1][3];
            g2 += xr[i2][rr][0]*wxf[2][0] + xr[i2][rr][1]*wxf[2][1] + xr[i2][rr][2]*wxf[2][2] + xr[i2][rr][3]*wxf[2][3];
            g3 += xr[i2][rr][0]*wxf[3][0] + xr[i2][rr][1]*wxf[3][1] + xr[i2][rr][2]*wxf[3][2] + xr[i2][rr][3]*wxf[3][3];
          }
          float ig = sigmoidf_(g0), fg = sigmoidf_(g1);
          float gg = tanhf_(g2),    og = sigmoidf_(g3);
          float c = fg*cst[i2][rr] + ig*gg;
          cst[i2][rr] = c;
          float hv = og * tanhf_(c);
          stash[cw*2176 + ((mp*2 + i2)*16 + quad*4 + rr)*34 + hf*16 + lc] = hv;
        }
      }
    }
    __syncthreads();

    // ---- packed h stores (tid>=256) + out-projection (tid<256) ----
    const bool skip1 = (r == 128 || r == 161);
    const bool skip2 = (r == 0   || r == 129);
    if (tid >= 256) {
      auto st16 = [&](_Float16* bp_, int chunk, unsigned long long u0, unsigned long long u1) {
        unsigned long long* p = (unsigned long long*)
          (bp_ + (((size_t)(mtile_e*32 + chunk)) << 9) + (oct*16 + m)*8);
        __hip_atomic_store(p,     u0, __ATOMIC_RELAXED, __HIP_MEMORY_SCOPE_AGENT);
        __hip_atomic_store(p + 1, u1, __ATOMIC_RELAXED, __HIP_MEMORY_SCOPE_AGENT);
      };
      if (!skip1) {                    // h1 from stash[0]
        v4f h0 = *(const v4f*)&stash[b_loc*34 + oct*8];
        v4f h1 = *(const v4f*)&stash[b_loc*34 + oct*8 + 4];
        union { _Float16 h8[8]; unsigned long long u[2]; } hu;
        #pragma unroll
        for (int j = 0; j < 4; j++) { hu.h8[j] = (_Float16)h0[j]; hu.h8[4+j] = (_Float16)h1[j]; }
        if (p1) {
          st16(AOv[wp], ht, hu.u[0], hu.u[1]);
          if (r == 127) st16(AFv[1], 16 + ht, hu.u[0], hu.u[1]);
        } else {
          st16(AFv[wp], 16 + ht, hu.u[0], hu.u[1]);
          st16(AOv[wp], ht, hu.u[0], hu.u[1]);
        }
      }
      if (!skip2) {                    // h2 from stash[1]
        v4f h0 = *(const v4f*)&stash[2176 + b_loc*34 + oct*8];
        v4f h1 = *(const v4f*)&stash[2176 + b_loc*34 + oct*8 + 4];
        union { _Float16 h8[8]; unsigned long long u[2]; } hu;
        #pragma unroll
        for (int j = 0; j < 4; j++) { hu.h8[j] = (_Float16)h0[j]; hu.h8[4+j] = (_Float16)h1[j]; }
        st16(AOv[wp], 16 + ht, hu.u[0], hu.u[1]);
        if (r == 128) { st16(AFv[0], ht, hu.u[0], hu.u[1]); st16(AFv[1], ht, hu.u[0], hu.u[1]); }
      }
    }
    if (tid < 256 && !p1 && r >= 130) {  // out(s) = h2f(s) @ Wl^T + bl, s = r-130
      const int s = r - 130;
      int bb = tid >> 2, o = tid & 3;
      float sa = (ht == 0) ? blv[o] : 0.f;
      const float* wl = Wl + (size_t)o*512 + ht*32;
      #pragma unroll
      for (int jj = 0; jj < 32; jj++) sa += stash[2176 + bb*34 + jj] * wl[jj];
      atomicAdd(&out[(((size_t)s*1024) + bt*64 + bb)*4 + o], sa);
    }
    __syncthreads();

    // ---- per-bt-group barrier: agent-relaxed add + relaxed poll ----
    if (tid == 0) {
      int* ctr = bar + bt*32;          // 128B-spaced counters
      __hip_atomic_fetch_add(ctr, 1, __ATOMIC_RELAXED, __HIP_MEMORY_SCOPE_AGENT);
      const int target = 16*(r+1);
      while (__hip_atomic_load(ctr, __ATOMIC_RELAXED, __HIP_MEMORY_SCOPE_AGENT) < target)
        __builtin_amdgcn_s_sleep(1);
    }
    __syncthreads();
  }
}

extern "C" void kernel_launch(void* const* d_in, const int* in_sizes, int n_in,
                              void* d_out, int out_size, void* d_ws, size_t ws_size,
                              hipStream_t stream) {
  const float* x    = (const float*)d_in[0];
  const float* Wih1 = (const float*)d_in[1];
  const float* Whh1 = (const float*)d_in[2];
  const float* bih1 = (const float*)d_in[3];
  const float* bhh1 = (const float*)d_in[4];
  const float* Wih2 = (const float*)d_in[5];
  const float* Whh2 = (const float*)d_in[6];
  const float* bih2 = (const float*)d_in[7];
  const float* bhh2 = (const float*)d_in[8];
  const float* Wl   = (const float*)d_in[9];
  const float* bl   = (const float*)d_in[10];

  char* ws = (char*)d_ws;
  int*      bar = (int*)(ws + OFF_BAR);
  _Float16* AO0 = (_Float16*)(ws + OFF_AO0);
  _Float16* AO1 = (_Float16*)(ws + OFF_AO1);
  _Float16* AF0 = (_Float16*)(ws + OFF_AF0);
  _Float16* AF1 = (_Float16*)(ws + OFF_AF1);
  _Float16* W1p = (_Float16*)(ws + OFF_W1);
  _Float16* W2p = (_Float16*)(ws + OFF_W2);
  float*    bs1 = (float*)(ws + OFF_B1);
  float*    bs2 = (float*)(ws + OFF_B2);

  // zero barrier + state buffers (h,c start at 0); zero out (atomic accumulation)
  hipMemsetAsync(ws, 0, (size_t)OFF_W1, stream);
  hipMemsetAsync(d_out, 0, (size_t)out_size * sizeof(float), stream);

  lstm_prep<<<2048, 256, 0, stream>>>(Whh1, Wih2, Whh2, bih1, bhh1, bih2, bhh2,
                                      W1p, W2p, bs1, bs2);
  lstm_main<<<256, 512, 0, stream>>>(x, Wih1, Wl, bl, AO0, AO1, AF0, AF1,
                                     W1p, W2p, bs1, bs2, bar, (float*)d_out);
}